// Round 4
// baseline (5308.792 us; speedup 1.0000x reference)
//
#include <hip/hip_runtime.h>
#include <stdint.h>

#define B_ 64
#define S_ 512
#define T_ 12
#define M_ (B_*S_)      // 32768 rows
#define NP_ 2048        // width of per-step projection P

__device__ __forceinline__ uint16_t f2bf(float f){
  union { float f; uint32_t u; } x; x.f = f;
  uint32_t r = x.u + 0x7FFFu + ((x.u >> 16) & 1u);   // RTNE
  return (uint16_t)(r >> 16);
}
__device__ __forceinline__ float bf2f(uint16_t u){
  union { float f; uint32_t u; } x; x.u = ((uint32_t)u) << 16; return x.f;
}
__device__ __forceinline__ float sigm(float x){ return 1.0f/(1.0f + expf(-x)); }

// ---------------------------------------------------------------------------
__global__ void zero16(uint4* __restrict__ p, long n16){
  const long i = (long)blockIdx.x * 256 + threadIdx.x;
  if (i < n16) p[i] = make_uint4(0,0,0,0);
}
__global__ void copy16(const uint4* __restrict__ s, uint4* __restrict__ d, long n16){
  const long i = (long)blockIdx.x * 256 + threadIdx.x;
  if (i < n16) d[i] = s[i];
}
__global__ void bf16_to_f32(const uint16_t* __restrict__ src, float* __restrict__ dst, long n){
  const long i = ((long)blockIdx.x * 256 + threadIdx.x) * 4;
  if (i + 3 < n) {
    const ushort4 v = *reinterpret_cast<const ushort4*>(src + i);
    float4 o; o.x=bf2f(v.x); o.y=bf2f(v.y); o.z=bf2f(v.z); o.w=bf2f(v.w);
    *reinterpret_cast<float4*>(dst + i) = o;
  }
}

// ---------------------------------------------------------------------------
// U_cat[256][2048] = [U_iou_r | U_iou_l | U_f0+U_f1 | U_f2+U_f3]  (fp32)
__global__ void build_ucat(const float* __restrict__ Ur, const float* __restrict__ Ul,
                           const float* __restrict__ f0, const float* __restrict__ f1,
                           const float* __restrict__ f2, const float* __restrict__ f3,
                           float* __restrict__ Ucat){
  int idx = blockIdx.x * 256 + threadIdx.x;       // 256*2048 total
  int k = idx >> 11;
  int n = idx & 2047;
  float v;
  if (n < 768)        v = Ur[k*768 + n];
  else if (n < 1536)  v = Ul[k*768 + (n-768)];
  else if (n < 1792) { int j = n-1536; v = f0[k*256+j] + f1[k*256+j]; }
  else               { int j = n-1792; v = f2[k*256+j] + f3[k*256+j]; }
  Ucat[idx] = v;
}

// ---------------------------------------------------------------------------
// C[M x N](bf16) = A[M x 256] @ Bm[256 x N] (+bias). A fp32 (ABF=0) or bf16 (ABF=1),
// rows optionally gathered. grid=(N/128, M/128), 256 thr, 128x128 tile, 8x8 micro.
template<int ABF>
__global__ __launch_bounds__(256)
void gemm_k256(const char* __restrict__ Ab, const int* __restrict__ row_ids,
               const float* __restrict__ Bm, const float* __restrict__ bias,
               uint16_t* __restrict__ C, int N)
{
  __shared__ float As[32][128];   // As[k][m]
  __shared__ float Bs[32][128];   // Bs[k][n]
  const int tid = threadIdx.x;
  const int tx = tid & 15, ty = tid >> 4;
  const long m0 = (long)blockIdx.y * 128;
  const int  n0 = blockIdx.x * 128;

  const int am = tid & 127;              // A staging: row in tile
  const int aq = tid >> 7;               // 0..1 k-half
  const long arid = row_ids ? (long)row_ids[m0 + am] : (m0 + am);
  const char* arow = Ab + arid * 256 * (ABF ? 2 : 4);

  const int bn = (tid & 31) * 4;         // B staging: col group
  const int bk = tid >> 5;               // 0..7

  float acc[8][8];
  #pragma unroll
  for (int i=0;i<8;i++){
    #pragma unroll
    for (int j=0;j<8;j++) acc[i][j]=0.0f;
  }

  for (int ks = 0; ks < 256; ks += 32) {
    #pragma unroll
    for (int it = 0; it < 4; ++it) {
      const int kl = aq*16 + it*4;
      float x0,x1,x2,x3;
      if (ABF) {
        const ushort4 v = *reinterpret_cast<const ushort4*>(arow + (ks+kl)*2);
        x0=bf2f(v.x); x1=bf2f(v.y); x2=bf2f(v.z); x3=bf2f(v.w);
      } else {
        const float4 v = *reinterpret_cast<const float4*>(arow + (ks+kl)*4);
        x0=v.x; x1=v.y; x2=v.z; x3=v.w;
      }
      As[kl+0][am]=x0; As[kl+1][am]=x1; As[kl+2][am]=x2; As[kl+3][am]=x3;
    }
    #pragma unroll
    for (int it = 0; it < 4; ++it) {
      const int kl = bk + it*8;
      *reinterpret_cast<float4*>(&Bs[kl][bn]) =
          *reinterpret_cast<const float4*>(Bm + (long)(ks+kl)*N + n0 + bn);
    }
    __syncthreads();
    #pragma unroll
    for (int kk = 0; kk < 32; ++kk) {
      float a[8], b[8];
      *reinterpret_cast<float4*>(&a[0]) = *reinterpret_cast<const float4*>(&As[kk][ty*4]);
      *reinterpret_cast<float4*>(&a[4]) = *reinterpret_cast<const float4*>(&As[kk][64+ty*4]);
      *reinterpret_cast<float4*>(&b[0]) = *reinterpret_cast<const float4*>(&Bs[kk][tx*4]);
      *reinterpret_cast<float4*>(&b[4]) = *reinterpret_cast<const float4*>(&Bs[kk][64+tx*4]);
      #pragma unroll
      for (int i=0;i<8;i++){
        #pragma unroll
        for (int j=0;j<8;j++) acc[i][j] = fmaf(a[i], b[j], acc[i][j]);
      }
    }
    __syncthreads();
  }

  float bs0[4] = {0,0,0,0}, bs1[4] = {0,0,0,0};
  if (bias) {
    #pragma unroll
    for (int j=0;j<4;j++){ bs0[j] = bias[n0+tx*4+j]; bs1[j] = bias[n0+64+tx*4+j]; }
  }
  #pragma unroll
  for (int i=0;i<8;i++) {
    const long r = m0 + ((i<4) ? (ty*4+i) : (64 + ty*4 + (i-4)));
    ushort4 o0, o1;
    o0.x = f2bf(acc[i][0]+bs0[0]); o0.y = f2bf(acc[i][1]+bs0[1]);
    o0.z = f2bf(acc[i][2]+bs0[2]); o0.w = f2bf(acc[i][3]+bs0[3]);
    o1.x = f2bf(acc[i][4]+bs1[0]); o1.y = f2bf(acc[i][5]+bs1[1]);
    o1.z = f2bf(acc[i][6]+bs1[2]); o1.w = f2bf(acc[i][7]+bs1[3]);
    *reinterpret_cast<ushort4*>(C + r*N + n0 + tx*4)      = o0;
    *reinterpret_cast<ushort4*>(C + r*N + n0 + 64 + tx*4) = o1;
  }
}

// ---------------------------------------------------------------------------
// Deterministic CSR inversion of td/tr/tl for every (t,b). One block per (t,b).
__global__ void build_csr(const int* __restrict__ td_g, const int* __restrict__ tr_g,
                          const int* __restrict__ tl_g,
                          int* __restrict__ csr_off, int* __restrict__ csr_val){
  const int t = blockIdx.x >> 6;
  const int b = blockIdx.x & 63;
  __shared__ int ids[S_];
  __shared__ int cnt[S_];
  __shared__ int off[S_+1];
  const int* srcs[3] = {td_g, tr_g, tl_g};
  const int s = threadIdx.x;                      // 512 threads
  for (int arr = 0; arr < 3; ++arr) {
    const int* src = srcs[arr] + ((long)b*T_ + t)*S_;   // layout [B][T][S]
    ids[s] = src[s];
    cnt[s] = 0;
    __syncthreads();
    atomicAdd(&cnt[ids[s]], 1);
    __syncthreads();
    if (s == 0) {
      int run = 0;
      for (int i=0;i<S_;i++){ off[i]=run; run+=cnt[i]; }
      off[S_]=run;
    }
    __syncthreads();
    const long base = (((long)arr*T_ + t)*B_ + b);
    int* offs = csr_off + base*(S_+1);
    int* vals = csr_val + base*S_;
    offs[s] = off[s];
    if (s == 0) {
      offs[S_] = off[S_];
      for (int i=0;i<S_;i++) cnt[i]=0;            // reuse as cursors
      for (int sp=0; sp<S_; ++sp) {               // stable fill: ascending source order
        int d = ids[sp];
        vals[off[d] + cnt[d]] = sp;
        cnt[d]++;
      }
    }
    __syncthreads();
  }
}

// ---------------------------------------------------------------------------
// Per-step destination-side update for rows [row0, row0+grid). Thread j = channel.
__global__ __launch_bounds__(256)
void step_update(const uint16_t* __restrict__ h_in, const float* __restrict__ c_in,
                 uint16_t* __restrict__ h_out, float* __restrict__ c_out,
                 const uint16_t* __restrict__ P,      // [Mc][2048] bf16, chunk-local rows
                 const uint16_t* __restrict__ ioux,   // [M][768]  bf16
                 const uint16_t* __restrict__ fx,     // [M][256]  bf16
                 const int* __restrict__ csr_off, const int* __restrict__ csr_val,
                 const int* __restrict__ tr_g, const int* __restrict__ tl_g,
                 int t, int row0)
{
  const long bs = (long)row0 + blockIdx.x;
  const int b = (int)(bs >> 9), s = (int)(bs & 511);
  const int j = threadIdx.x;          // 0..255

  const int* off_td = csr_off + (((long)0*T_ + t)*B_ + b)*(S_+1);
  const int td0 = off_td[s], td1 = off_td[s+1];
  const bool masked = (s != 0) && (td1 > td0);
  if (!masked) {
    h_out[bs*256 + j] = h_in[bs*256 + j];
    c_out[bs*256 + j] = c_in[bs*256 + j];
    return;
  }
  const int* off_tr = csr_off + (((long)1*T_ + t)*B_ + b)*(S_+1);
  const int* off_tl = csr_off + (((long)2*T_ + t)*B_ + b)*(S_+1);
  const int* val_td = csr_val + (((long)0*T_ + t)*B_ + b)*S_;
  const int* val_tr = csr_val + (((long)1*T_ + t)*B_ + b)*S_;
  const int* val_tl = csr_val + (((long)2*T_ + t)*B_ + b)*S_;

  const long lbase = (long)(b<<9) - row0;             // chunk-local row base for P

  const long ib = bs*768;
  float ai = bf2f(ioux[ib + j]);
  float ao = bf2f(ioux[ib + 256 + j]);
  float au = bf2f(ioux[ib + 512 + j]);
  for (int p = off_tr[s]; p < off_tr[s+1]; ++p) {     // sources s' with tr[s']==s
    const long pr = (lbase + val_tr[p]) * NP_;
    ai += bf2f(P[pr + j]); ao += bf2f(P[pr + 256 + j]); au += bf2f(P[pr + 512 + j]);
  }
  for (int p = off_tl[s]; p < off_tl[s+1]; ++p) {     // sources s' with tl[s']==s
    const long pr = (lbase + val_tl[p]) * NP_;
    ai += bf2f(P[pr + 768 + j]); ao += bf2f(P[pr + 1024 + j]); au += bf2f(P[pr + 1280 + j]);
  }
  const float gi = sigm(ai);
  const float go = sigm(ao);
  const float gu = tanhf(au);
  const float fxv = bf2f(fx[bs*256 + j]);             // f_x at the DESTINATION row
  float cacc = gi * gu;
  const int* trrow = tr_g + ((long)b*T_ + t)*S_;
  const int* tlrow = tl_g + ((long)b*T_ + t)*S_;
  for (int p = td0; p < td1; ++p) {                   // children s' with td[s']==s
    const int sp = val_td[p];
    const long prr = (lbase + trrow[sp]) * NP_;       // gather P_f01 at tr[s']
    const long prl = (lbase + tlrow[sp]) * NP_;       // gather P_f23 at tl[s']
    const float f = sigm(fxv + bf2f(P[prr + 1536 + j]) + bf2f(P[prl + 1792 + j]));
    cacc += f * c_in[((long)(b<<9) + sp)*256 + j];
  }
  h_out[bs*256 + j] = f2bf(go * tanhf(cacc));
  c_out[bs*256 + j] = cacc;
}

// ---------------------------------------------------------------------------
__global__ void root_kernel(const uint16_t* __restrict__ h, const int* __restrict__ td_g,
                            float* __restrict__ out_root){
  const int b = blockIdx.x;
  __shared__ int red[256];
  const int* td = td_g + ((long)b*T_ + (T_-1))*S_;
  int m = 0;
  for (int s = threadIdx.x; s < S_; s += 256) m = max(m, td[s]);
  red[threadIdx.x] = m; __syncthreads();
  for (int w = 128; w > 0; w >>= 1){
    if (threadIdx.x < w) red[threadIdx.x] = max(red[threadIdx.x], red[threadIdx.x+w]);
    __syncthreads();
  }
  const int root = red[0];
  out_root[b*256 + threadIdx.x] = bf2f(h[((long)b*512 + root)*256 + threadIdx.x]);
}

// ---------------------------------------------------------------------------
extern "C" void kernel_launch(void* const* d_in, const int* in_sizes, int n_in,
                              void* d_out, int out_size, void* d_ws, size_t ws_size,
                              hipStream_t stream) {
  const int*   input_ids  = (const int*)  d_in[0];
  const int*   tree_ids   = (const int*)  d_in[1];
  const int*   tree_ids_r = (const int*)  d_in[2];
  const int*   tree_ids_l = (const int*)  d_in[3];
  const float* emb        = (const float*)d_in[4];
  const float* W_ioux     = (const float*)d_in[5];
  const float* b_ioux     = (const float*)d_in[6];
  const float* U_iou_r    = (const float*)d_in[7];
  const float* U_iou_l    = (const float*)d_in[8];
  const float* W_f        = (const float*)d_in[9];
  const float* b_f        = (const float*)d_in[10];
  const float* U_f0       = (const float*)d_in[11];
  const float* U_f1       = (const float*)d_in[12];
  const float* U_f2       = (const float*)d_in[13];
  const float* U_f3       = (const float*)d_in[14];
  float* out = (float*)d_out;                  // FP32 outputs: h | c | h_root

  // --- workspace layout: fixed ~180 MB + adaptive P chunk ---
  size_t woff = 0;
  auto alloc = [&](size_t bytes)->char*{
    char* p = (char*)d_ws + woff; woff += (bytes + 255) & ~(size_t)255; return p;
  };
  uint16_t* ioux = (uint16_t*)alloc((size_t)M_*768*2);      // 50.3 MB
  uint16_t* fx   = (uint16_t*)alloc((size_t)M_*256*2);      // 16.8 MB
  float*    Ucat = (float*)   alloc((size_t)256*NP_*4);     //  2.1 MB
  uint16_t* hA   = (uint16_t*)alloc((size_t)M_*256*2);      // 16.8 MB (hA,cA contiguous)
  float*    cA   = (float*)   alloc((size_t)M_*256*4);      // 33.6 MB
  uint16_t* hB   = (uint16_t*)alloc((size_t)M_*256*2);
  float*    cB   = (float*)   alloc((size_t)M_*256*4);
  int* csr_off   = (int*)     alloc((size_t)3*T_*B_*(S_+1)*4);
  int* csr_val   = (int*)     alloc((size_t)3*T_*B_*S_*4);
  int CB = 64;                                               // batches per P chunk
  while (CB > 1 && woff + (size_t)CB*S_*NP_*2 > ws_size) CB >>= 1;
  uint16_t* P    = (uint16_t*)alloc((size_t)CB*S_*NP_*2);   // ≤134 MB (bf16)

  // --- setup ---
  build_ucat<<<(256*NP_)/256, 256, 0, stream>>>(U_iou_r, U_iou_l, U_f0, U_f1, U_f2, U_f3, Ucat);
  gemm_k256<0><<<dim3(768/128, M_/128), 256, 0, stream>>>((const char*)emb, input_ids, W_ioux, b_ioux, ioux, 768);
  gemm_k256<0><<<dim3(256/128, M_/128), 256, 0, stream>>>((const char*)emb, input_ids, W_f, b_f, fx, 256);
  build_csr<<<T_*B_, S_, 0, stream>>>(tree_ids, tree_ids_r, tree_ids_l, csr_off, csr_val);
  zero16<<<12288, 256, 0, stream>>>((uint4*)hA, 3145728L);   // zero hA+cA (contiguous 50.3MB)

  // --- T sequential steps, ping-pong state, batch-chunked projection ---
  uint16_t *hc = hA, *hn = hB; float *cc = cA, *cn = cB;
  for (int t = 0; t < T_; ++t) {
    for (int b0 = 0; b0 < B_; b0 += CB) {
      const int row0 = b0 * S_;
      const int Mc   = CB * S_;
      gemm_k256<1><<<dim3(NP_/128, Mc/128), 256, 0, stream>>>(
          (const char*)(hc + (long)row0*256), nullptr, Ucat, nullptr, P, NP_);
      step_update<<<Mc, 256, 0, stream>>>(hc, cc, hn, cn, P, ioux, fx,
                                          csr_off, csr_val, tree_ids_r, tree_ids_l,
                                          t, row0);
    }
    uint16_t* th = hc; hc = hn; hn = th;
    float*    tc = cc; cc = cn; cn = tc;
  }

  // --- outputs (fp32): h | c | h_root ---
  bf16_to_f32<<<8192, 256, 0, stream>>>(hc, out, (long)M_*256);                        // h
  copy16<<<8192, 256, 0, stream>>>((const uint4*)cc, (uint4*)(out + (long)M_*256), 2097152L); // c
  root_kernel<<<B_, 256, 0, stream>>>(hc, tree_ids, out + 2L*M_*256);                  // h_root
}

// Round 5
// 1885.182 us; speedup vs baseline: 2.8161x; 2.8161x over previous
//
#include <hip/hip_runtime.h>
#include <stdint.h>

#define B_ 64
#define S_ 512
#define T_ 12
#define M_ (B_*S_)      // 32768 rows
#define NP_ 2048        // width of per-step projection P

typedef __attribute__((ext_vector_type(8))) short bf16x8;   // 8 bf16 = 4 VGPR
typedef __attribute__((ext_vector_type(4))) float f32x4;    // MFMA accumulator

__device__ __forceinline__ uint16_t f2bf(float f){
  union { float f; uint32_t u; } x; x.f = f;
  uint32_t r = x.u + 0x7FFFu + ((x.u >> 16) & 1u);   // RTNE
  return (uint16_t)(r >> 16);
}
__device__ __forceinline__ float bf2f(uint16_t u){
  union { float f; uint32_t u; } x; x.u = ((uint32_t)u) << 16; return x.f;
}
__device__ __forceinline__ float sigm(float x){ return 1.0f/(1.0f + expf(-x)); }

// ---------------------------------------------------------------------------
__global__ void zero16(uint4* __restrict__ p, long n16){
  const long i = (long)blockIdx.x * 256 + threadIdx.x;
  if (i < n16) p[i] = make_uint4(0,0,0,0);
}
__global__ void copy16(const uint4* __restrict__ s, uint4* __restrict__ d, long n16){
  const long i = (long)blockIdx.x * 256 + threadIdx.x;
  if (i < n16) d[i] = s[i];
}
__global__ void bf16_to_f32(const uint16_t* __restrict__ src, float* __restrict__ dst, long n){
  const long i = ((long)blockIdx.x * 256 + threadIdx.x) * 4;
  if (i + 3 < n) {
    const ushort4 v = *reinterpret_cast<const ushort4*>(src + i);
    float4 o; o.x=bf2f(v.x); o.y=bf2f(v.y); o.z=bf2f(v.z); o.w=bf2f(v.w);
    *reinterpret_cast<float4*>(dst + i) = o;
  }
}

// ---------------------------------------------------------------------------
// UcatT[2048][256] bf16, UcatT[n][k] = [U_iou_r | U_iou_l | U_f0+U_f1 | U_f2+U_f3][k][n]
__global__ void build_ucatT(const float* __restrict__ Ur, const float* __restrict__ Ul,
                            const float* __restrict__ f0, const float* __restrict__ f1,
                            const float* __restrict__ f2, const float* __restrict__ f3,
                            uint16_t* __restrict__ UcatT){
  const int idx = blockIdx.x * 256 + threadIdx.x;   // 2048*256 total
  const int n = idx >> 8, k = idx & 255;
  float v;
  if (n < 768)        v = Ur[k*768 + n];
  else if (n < 1536)  v = Ul[k*768 + (n-768)];
  else if (n < 1792) { int j = n-1536; v = f0[k*256+j] + f1[k*256+j]; }
  else               { int j = n-1792; v = f2[k*256+j] + f3[k*256+j]; }
  UcatT[(long)n*256 + k] = f2bf(v);
}

// WT[ncols][256] bf16 = W[256][ncols]^T  (grid = ncols, 256 threads)
__global__ void transpose_bf16(const float* __restrict__ src, uint16_t* __restrict__ dst, int ncols){
  const int idx = blockIdx.x * 256 + threadIdx.x;
  const int n = idx >> 8, k = idx & 255;
  dst[(long)n*256 + k] = f2bf(src[(long)k*ncols + n]);
}

// ---------------------------------------------------------------------------
// MFMA GEMM: C[M x N](bf16) = gather(A)[M x 256] @ BT[N x 256]^T (+bias)
// A fp32 (ABF=0) or bf16 (ABF=1); rows gathered via row_ids if non-null.
// BT is bf16, k-minor. grid=(N/128, M/128), 256 thr = 4 waves, wave = 64x64 out.
// mfma_f32_16x16x32_bf16: A row=lane&15,k=(lane>>4)*8+e; B col=lane&15,same k;
// D col=lane&15, row=(lane>>4)*4+reg  [m89-verified mapping].
template<int ABF>
__global__ __launch_bounds__(256)
void mfma_gemm(const char* __restrict__ Ab, const int* __restrict__ row_ids,
               const uint16_t* __restrict__ BT, const float* __restrict__ bias,
               uint16_t* __restrict__ C, int N)
{
  __shared__ uint16_t As[128][40];   // [m][k], +8 pad -> 80B rows (16B aligned)
  __shared__ uint16_t Bs[128][40];   // [n][k]
  const int tid  = threadIdx.x;
  const int lane = tid & 63;
  const int wave = tid >> 6;
  const int wr = wave >> 1, wc = wave & 1;          // 2x2 wave grid
  const long m0 = (long)blockIdx.y * 128;
  const int  n0 = blockIdx.x * 128;

  const int srow = tid >> 1;                        // staging row 0..127
  const int sseg = (tid & 1) * 16;                  // k-offset 0 or 16
  const long arid = row_ids ? (long)row_ids[m0 + srow] : (m0 + srow);

  f32x4 acc[4][4];
  #pragma unroll
  for (int i=0;i<4;i++)
    #pragma unroll
    for (int j=0;j<4;j++) acc[i][j] = (f32x4){0.f,0.f,0.f,0.f};

  for (int ks = 0; ks < 256; ks += 32) {
    // --- stage A tile (128 x 32 bf16) ---
    if (ABF) {
      const uint16_t* src = (const uint16_t*)Ab + arid*256 + ks + sseg;
      *reinterpret_cast<uint4*>(&As[srow][sseg])     = *reinterpret_cast<const uint4*>(src);
      *reinterpret_cast<uint4*>(&As[srow][sseg + 8]) = *reinterpret_cast<const uint4*>(src + 8);
    } else {
      const float* sf = (const float*)Ab + arid*256 + ks + sseg;
      uint16_t tmp[16];
      #pragma unroll
      for (int e=0;e<16;e++) tmp[e] = f2bf(sf[e]);
      *reinterpret_cast<uint4*>(&As[srow][sseg])     = *reinterpret_cast<const uint4*>(&tmp[0]);
      *reinterpret_cast<uint4*>(&As[srow][sseg + 8]) = *reinterpret_cast<const uint4*>(&tmp[8]);
    }
    // --- stage B tile (128 cols x 32 k, from BT row-major k-minor) ---
    {
      const uint16_t* src = BT + (long)(n0 + srow)*256 + ks + sseg;
      *reinterpret_cast<uint4*>(&Bs[srow][sseg])     = *reinterpret_cast<const uint4*>(src);
      *reinterpret_cast<uint4*>(&Bs[srow][sseg + 8]) = *reinterpret_cast<const uint4*>(src + 8);
    }
    __syncthreads();

    bf16x8 af[4], bf[4];
    #pragma unroll
    for (int i=0;i<4;i++)
      af[i] = *reinterpret_cast<const bf16x8*>(&As[wr*64 + i*16 + (lane & 15)][(lane >> 4)*8]);
    #pragma unroll
    for (int j=0;j<4;j++)
      bf[j] = *reinterpret_cast<const bf16x8*>(&Bs[wc*64 + j*16 + (lane & 15)][(lane >> 4)*8]);
    #pragma unroll
    for (int i=0;i<4;i++)
      #pragma unroll
      for (int j=0;j<4;j++)
        acc[i][j] = __builtin_amdgcn_mfma_f32_16x16x32_bf16(af[i], bf[j], acc[i][j], 0, 0, 0);
    __syncthreads();
  }

  const int col16 = lane & 15, rquad = lane >> 4;
  #pragma unroll
  for (int j=0;j<4;j++){
    const int col = n0 + wc*64 + j*16 + col16;
    const float bv = bias ? bias[col] : 0.0f;
    #pragma unroll
    for (int i=0;i<4;i++){
      const long rbase = m0 + wr*64 + i*16 + rquad*4;
      #pragma unroll
      for (int r=0;r<4;r++)
        C[(rbase + r)*N + col] = f2bf(acc[i][j][r] + bv);
    }
  }
}

// ---------------------------------------------------------------------------
// Deterministic CSR inversion of td/tr/tl for every (t,b). One block per (t,b).
__global__ void build_csr(const int* __restrict__ td_g, const int* __restrict__ tr_g,
                          const int* __restrict__ tl_g,
                          int* __restrict__ csr_off, int* __restrict__ csr_val){
  const int t = blockIdx.x >> 6;
  const int b = blockIdx.x & 63;
  __shared__ int ids[S_];
  __shared__ int cnt[S_];
  __shared__ int off[S_+1];
  const int* srcs[3] = {td_g, tr_g, tl_g};
  const int s = threadIdx.x;                      // 512 threads
  for (int arr = 0; arr < 3; ++arr) {
    const int* src = srcs[arr] + ((long)b*T_ + t)*S_;   // layout [B][T][S]
    ids[s] = src[s];
    cnt[s] = 0;
    __syncthreads();
    atomicAdd(&cnt[ids[s]], 1);
    __syncthreads();
    if (s == 0) {
      int run = 0;
      for (int i=0;i<S_;i++){ off[i]=run; run+=cnt[i]; }
      off[S_]=run;
    }
    __syncthreads();
    const long base = (((long)arr*T_ + t)*B_ + b);
    int* offs = csr_off + base*(S_+1);
    int* vals = csr_val + base*S_;
    offs[s] = off[s];
    if (s == 0) {
      offs[S_] = off[S_];
      for (int i=0;i<S_;i++) cnt[i]=0;            // reuse as cursors
      for (int sp=0; sp<S_; ++sp) {               // stable fill: ascending source order
        int d = ids[sp];
        vals[off[d] + cnt[d]] = sp;
        cnt[d]++;
      }
    }
    __syncthreads();
  }
}

// ---------------------------------------------------------------------------
// Per-step destination-side update for rows [row0, row0+grid). Thread j = channel.
__global__ __launch_bounds__(256)
void step_update(const uint16_t* __restrict__ h_in, const float* __restrict__ c_in,
                 uint16_t* __restrict__ h_out, float* __restrict__ c_out,
                 const uint16_t* __restrict__ P,      // [Mc][2048] bf16, chunk-local rows
                 const uint16_t* __restrict__ ioux,   // [M][768]  bf16
                 const uint16_t* __restrict__ fx,     // [M][256]  bf16
                 const int* __restrict__ csr_off, const int* __restrict__ csr_val,
                 const int* __restrict__ tr_g, const int* __restrict__ tl_g,
                 int t, int row0)
{
  const long bs = (long)row0 + blockIdx.x;
  const int b = (int)(bs >> 9), s = (int)(bs & 511);
  const int j = threadIdx.x;          // 0..255

  const int* off_td = csr_off + (((long)0*T_ + t)*B_ + b)*(S_+1);
  const int td0 = off_td[s], td1 = off_td[s+1];
  const bool masked = (s != 0) && (td1 > td0);
  if (!masked) {
    h_out[bs*256 + j] = h_in[bs*256 + j];
    c_out[bs*256 + j] = c_in[bs*256 + j];
    return;
  }
  const int* off_tr = csr_off + (((long)1*T_ + t)*B_ + b)*(S_+1);
  const int* off_tl = csr_off + (((long)2*T_ + t)*B_ + b)*(S_+1);
  const int* val_td = csr_val + (((long)0*T_ + t)*B_ + b)*S_;
  const int* val_tr = csr_val + (((long)1*T_ + t)*B_ + b)*S_;
  const int* val_tl = csr_val + (((long)2*T_ + t)*B_ + b)*S_;

  const long lbase = (long)(b<<9) - row0;             // chunk-local row base for P

  const long ib = bs*768;
  float ai = bf2f(ioux[ib + j]);
  float ao = bf2f(ioux[ib + 256 + j]);
  float au = bf2f(ioux[ib + 512 + j]);
  for (int p = off_tr[s]; p < off_tr[s+1]; ++p) {     // sources s' with tr[s']==s
    const long pr = (lbase + val_tr[p]) * NP_;
    ai += bf2f(P[pr + j]); ao += bf2f(P[pr + 256 + j]); au += bf2f(P[pr + 512 + j]);
  }
  for (int p = off_tl[s]; p < off_tl[s+1]; ++p) {     // sources s' with tl[s']==s
    const long pr = (lbase + val_tl[p]) * NP_;
    ai += bf2f(P[pr + 768 + j]); ao += bf2f(P[pr + 1024 + j]); au += bf2f(P[pr + 1280 + j]);
  }
  const float gi = sigm(ai);
  const float go = sigm(ao);
  const float gu = tanhf(au);
  const float fxv = bf2f(fx[bs*256 + j]);             // f_x at the DESTINATION row
  float cacc = gi * gu;
  const int* trrow = tr_g + ((long)b*T_ + t)*S_;
  const int* tlrow = tl_g + ((long)b*T_ + t)*S_;
  for (int p = td0; p < td1; ++p) {                   // children s' with td[s']==s
    const int sp = val_td[p];
    const long prr = (lbase + trrow[sp]) * NP_;       // gather P_f01 at tr[s']
    const long prl = (lbase + tlrow[sp]) * NP_;       // gather P_f23 at tl[s']
    const float f = sigm(fxv + bf2f(P[prr + 1536 + j]) + bf2f(P[prl + 1792 + j]));
    cacc += f * c_in[((long)(b<<9) + sp)*256 + j];
  }
  h_out[bs*256 + j] = f2bf(go * tanhf(cacc));
  c_out[bs*256 + j] = cacc;
}

// ---------------------------------------------------------------------------
__global__ void root_kernel(const uint16_t* __restrict__ h, const int* __restrict__ td_g,
                            float* __restrict__ out_root){
  const int b = blockIdx.x;
  __shared__ int red[256];
  const int* td = td_g + ((long)b*T_ + (T_-1))*S_;
  int m = 0;
  for (int s = threadIdx.x; s < S_; s += 256) m = max(m, td[s]);
  red[threadIdx.x] = m; __syncthreads();
  for (int w = 128; w > 0; w >>= 1){
    if (threadIdx.x < w) red[threadIdx.x] = max(red[threadIdx.x], red[threadIdx.x+w]);
    __syncthreads();
  }
  const int root = red[0];
  out_root[b*256 + threadIdx.x] = bf2f(h[((long)b*512 + root)*256 + threadIdx.x]);
}

// ---------------------------------------------------------------------------
extern "C" void kernel_launch(void* const* d_in, const int* in_sizes, int n_in,
                              void* d_out, int out_size, void* d_ws, size_t ws_size,
                              hipStream_t stream) {
  const int*   input_ids  = (const int*)  d_in[0];
  const int*   tree_ids   = (const int*)  d_in[1];
  const int*   tree_ids_r = (const int*)  d_in[2];
  const int*   tree_ids_l = (const int*)  d_in[3];
  const float* emb        = (const float*)d_in[4];
  const float* W_ioux     = (const float*)d_in[5];
  const float* b_ioux     = (const float*)d_in[6];
  const float* U_iou_r    = (const float*)d_in[7];
  const float* U_iou_l    = (const float*)d_in[8];
  const float* W_f        = (const float*)d_in[9];
  const float* b_f        = (const float*)d_in[10];
  const float* U_f0       = (const float*)d_in[11];
  const float* U_f1       = (const float*)d_in[12];
  const float* U_f2       = (const float*)d_in[13];
  const float* U_f3       = (const float*)d_in[14];
  float* out = (float*)d_out;                  // FP32 outputs: h | c | h_root

  // --- workspace layout: fixed ~179 MB + adaptive P chunk ---
  size_t woff = 0;
  auto alloc = [&](size_t bytes)->char*{
    char* p = (char*)d_ws + woff; woff += (bytes + 255) & ~(size_t)255; return p;
  };
  uint16_t* ioux   = (uint16_t*)alloc((size_t)M_*768*2);      // 50.3 MB
  uint16_t* fx     = (uint16_t*)alloc((size_t)M_*256*2);      // 16.8 MB
  uint16_t* hA     = (uint16_t*)alloc((size_t)M_*256*2);      // 16.8 MB (hA,cA contiguous)
  float*    cA     = (float*)   alloc((size_t)M_*256*4);      // 33.6 MB
  uint16_t* hB     = (uint16_t*)alloc((size_t)M_*256*2);
  float*    cB     = (float*)   alloc((size_t)M_*256*4);
  int* csr_off     = (int*)     alloc((size_t)3*T_*B_*(S_+1)*4);
  int* csr_val     = (int*)     alloc((size_t)3*T_*B_*S_*4);
  uint16_t* UcatT  = (uint16_t*)alloc((size_t)NP_*256*2);     //  1.05 MB
  uint16_t* WiouxT = (uint16_t*)alloc((size_t)768*256*2);     //  0.39 MB
  uint16_t* WfT    = (uint16_t*)alloc((size_t)256*256*2);     //  0.13 MB
  int CB = 64;                                                // batches per P chunk
  while (CB > 1 && woff + (size_t)CB*S_*NP_*2 > ws_size) CB >>= 1;
  uint16_t* P      = (uint16_t*)alloc((size_t)CB*S_*NP_*2);   // ≤134 MB (bf16)

  // --- setup: transposed bf16 weights, then MFMA setup GEMMs ---
  build_ucatT<<<2048, 256, 0, stream>>>(U_iou_r, U_iou_l, U_f0, U_f1, U_f2, U_f3, UcatT);
  transpose_bf16<<<768, 256, 0, stream>>>(W_ioux, WiouxT, 768);
  transpose_bf16<<<256, 256, 0, stream>>>(W_f, WfT, 256);
  mfma_gemm<0><<<dim3(768/128, M_/128), 256, 0, stream>>>((const char*)emb, input_ids, WiouxT, b_ioux, ioux, 768);
  mfma_gemm<0><<<dim3(256/128, M_/128), 256, 0, stream>>>((const char*)emb, input_ids, WfT, b_f, fx, 256);
  build_csr<<<T_*B_, S_, 0, stream>>>(tree_ids, tree_ids_r, tree_ids_l, csr_off, csr_val);
  zero16<<<12288, 256, 0, stream>>>((uint4*)hA, 3145728L);   // zero hA+cA (contiguous 50.3MB)

  // --- T sequential steps, ping-pong state, batch-chunked projection ---
  uint16_t *hc = hA, *hn = hB; float *cc = cA, *cn = cB;
  for (int t = 0; t < T_; ++t) {
    for (int b0 = 0; b0 < B_; b0 += CB) {
      const int row0 = b0 * S_;
      const int Mc   = CB * S_;
      mfma_gemm<1><<<dim3(NP_/128, Mc/128), 256, 0, stream>>>(
          (const char*)(hc + (long)row0*256), nullptr, UcatT, nullptr, P, NP_);
      step_update<<<Mc, 256, 0, stream>>>(hc, cc, hn, cn, P, ioux, fx,
                                          csr_off, csr_val, tree_ids_r, tree_ids_l,
                                          t, row0);
    }
    uint16_t* th = hc; hc = hn; hn = th;
    float*    tc = cc; cc = cn; cn = tc;
  }

  // --- outputs (fp32): h | c | h_root ---
  bf16_to_f32<<<8192, 256, 0, stream>>>(hc, out, (long)M_*256);                        // h
  copy16<<<8192, 256, 0, stream>>>((const uint4*)cc, (uint4*)(out + (long)M_*256), 2097152L); // c
  root_kernel<<<B_, 256, 0, stream>>>(hc, tree_ids, out + 2L*M_*256);                  // h_root
}

// Round 6
// 1653.303 us; speedup vs baseline: 3.2110x; 1.1403x over previous
//
#include <hip/hip_runtime.h>
#include <stdint.h>

#define B_ 64
#define S_ 512
#define T_ 12
#define M_ (B_*S_)      // 32768 rows
#define NP_ 2048        // width of per-step projection P

typedef __attribute__((ext_vector_type(8))) short bf16x8;   // 8 bf16 = 4 VGPR
typedef __attribute__((ext_vector_type(4))) float f32x4;    // MFMA accumulator

__device__ __forceinline__ uint16_t f2bf(float f){
  union { float f; uint32_t u; } x; x.f = f;
  uint32_t r = x.u + 0x7FFFu + ((x.u >> 16) & 1u);   // RTNE
  return (uint16_t)(r >> 16);
}
__device__ __forceinline__ float bf2f(uint16_t u){
  union { float f; uint32_t u; } x; x.u = ((uint32_t)u) << 16; return x.f;
}
__device__ __forceinline__ float sigm(float x){ return 1.0f/(1.0f + expf(-x)); }

// async global->LDS, 16B per lane; LDS dest = wave-uniform base + lane*16
__device__ __forceinline__ void gload16(const uint16_t* g, uint16_t* l){
  __builtin_amdgcn_global_load_lds(
      (const __attribute__((address_space(1))) uint32_t*)g,
      (__attribute__((address_space(3))) uint32_t*)l, 16, 0, 0);
}

// ---------------------------------------------------------------------------
__global__ void zero16(uint4* __restrict__ p, long n16){
  const long i = (long)blockIdx.x * 256 + threadIdx.x;
  if (i < n16) p[i] = make_uint4(0,0,0,0);
}
__global__ void copy16(const uint4* __restrict__ s, uint4* __restrict__ d, long n16){
  const long i = (long)blockIdx.x * 256 + threadIdx.x;
  if (i < n16) d[i] = s[i];
}
__global__ void bf16_to_f32(const uint16_t* __restrict__ src, float* __restrict__ dst, long n){
  const long i = ((long)blockIdx.x * 256 + threadIdx.x) * 4;
  if (i + 3 < n) {
    const ushort4 v = *reinterpret_cast<const ushort4*>(src + i);
    float4 o; o.x=bf2f(v.x); o.y=bf2f(v.y); o.z=bf2f(v.z); o.w=bf2f(v.w);
    *reinterpret_cast<float4*>(dst + i) = o;
  }
}

// ---------------------------------------------------------------------------
// UcatT[2048][256] bf16, UcatT[n][k] = [U_iou_r | U_iou_l | U_f0+U_f1 | U_f2+U_f3][k][n]
__global__ void build_ucatT(const float* __restrict__ Ur, const float* __restrict__ Ul,
                            const float* __restrict__ f0, const float* __restrict__ f1,
                            const float* __restrict__ f2, const float* __restrict__ f3,
                            uint16_t* __restrict__ UcatT){
  const int idx = blockIdx.x * 256 + threadIdx.x;   // 2048*256 total
  const int n = idx >> 8, k = idx & 255;
  float v;
  if (n < 768)        v = Ur[k*768 + n];
  else if (n < 1536)  v = Ul[k*768 + (n-768)];
  else if (n < 1792) { int j = n-1536; v = f0[k*256+j] + f1[k*256+j]; }
  else               { int j = n-1792; v = f2[k*256+j] + f3[k*256+j]; }
  UcatT[(long)n*256 + k] = f2bf(v);
}

// WT[ncols][256] bf16 = W[256][ncols]^T  (grid = ncols, 256 threads)
__global__ void transpose_bf16(const float* __restrict__ src, uint16_t* __restrict__ dst, int ncols){
  const int idx = blockIdx.x * 256 + threadIdx.x;
  const int n = idx >> 8, k = idx & 255;
  dst[(long)n*256 + k] = f2bf(src[(long)k*ncols + n]);
}

// ---------------------------------------------------------------------------
// Setup-path MFMA GEMM (fp32 A with row gather): padded-LDS manual staging.
template<int ABF>
__global__ __launch_bounds__(256)
void mfma_gemm(const char* __restrict__ Ab, const int* __restrict__ row_ids,
               const uint16_t* __restrict__ BT, const float* __restrict__ bias,
               uint16_t* __restrict__ C, int N)
{
  __shared__ uint16_t As[128][40];   // [m][k], +8 pad -> 80B rows
  __shared__ uint16_t Bs[128][40];   // [n][k]
  const int tid  = threadIdx.x;
  const int lane = tid & 63;
  const int wave = tid >> 6;
  const int wr = wave >> 1, wc = wave & 1;
  const long m0 = (long)blockIdx.y * 128;
  const int  n0 = blockIdx.x * 128;

  const int srow = tid >> 1;
  const int sseg = (tid & 1) * 16;
  const long arid = row_ids ? (long)row_ids[m0 + srow] : (m0 + srow);

  f32x4 acc[4][4];
  #pragma unroll
  for (int i=0;i<4;i++)
    #pragma unroll
    for (int j=0;j<4;j++) acc[i][j] = (f32x4){0.f,0.f,0.f,0.f};

  for (int ks = 0; ks < 256; ks += 32) {
    if (ABF) {
      const uint16_t* src = (const uint16_t*)Ab + arid*256 + ks + sseg;
      *reinterpret_cast<uint4*>(&As[srow][sseg])     = *reinterpret_cast<const uint4*>(src);
      *reinterpret_cast<uint4*>(&As[srow][sseg + 8]) = *reinterpret_cast<const uint4*>(src + 8);
    } else {
      const float* sf = (const float*)Ab + arid*256 + ks + sseg;
      uint16_t tmp[16];
      #pragma unroll
      for (int e=0;e<16;e++) tmp[e] = f2bf(sf[e]);
      *reinterpret_cast<uint4*>(&As[srow][sseg])     = *reinterpret_cast<const uint4*>(&tmp[0]);
      *reinterpret_cast<uint4*>(&As[srow][sseg + 8]) = *reinterpret_cast<const uint4*>(&tmp[8]);
    }
    {
      const uint16_t* src = BT + (long)(n0 + srow)*256 + ks + sseg;
      *reinterpret_cast<uint4*>(&Bs[srow][sseg])     = *reinterpret_cast<const uint4*>(src);
      *reinterpret_cast<uint4*>(&Bs[srow][sseg + 8]) = *reinterpret_cast<const uint4*>(src + 8);
    }
    __syncthreads();

    bf16x8 af[4], bfv[4];
    #pragma unroll
    for (int i=0;i<4;i++)
      af[i] = *reinterpret_cast<const bf16x8*>(&As[wr*64 + i*16 + (lane & 15)][(lane >> 4)*8]);
    #pragma unroll
    for (int j=0;j<4;j++)
      bfv[j] = *reinterpret_cast<const bf16x8*>(&Bs[wc*64 + j*16 + (lane & 15)][(lane >> 4)*8]);
    #pragma unroll
    for (int i=0;i<4;i++)
      #pragma unroll
      for (int j=0;j<4;j++)
        acc[i][j] = __builtin_amdgcn_mfma_f32_16x16x32_bf16(af[i], bfv[j], acc[i][j], 0, 0, 0);
    __syncthreads();
  }

  const int col16 = lane & 15, rquad = lane >> 4;
  #pragma unroll
  for (int j=0;j<4;j++){
    const int col = n0 + wc*64 + j*16 + col16;
    const float bv = bias ? bias[col] : 0.0f;
    #pragma unroll
    for (int i=0;i<4;i++){
      const long rbase = m0 + wr*64 + i*16 + rquad*4;
      #pragma unroll
      for (int r=0;r<4;r++)
        C[(rbase + r)*N + col] = f2bf(acc[i][j][r] + bv);
    }
  }
}

// ---------------------------------------------------------------------------
// Step-path MFMA GEMM (bf16 A, no gather): global_load_lds staging, linear LDS,
// XOR seg-swizzle (seg' = seg ^ ((row>>1)&3)) applied to global source AND ds_read.
__global__ __launch_bounds__(256)
void gemm_step(const uint16_t* __restrict__ A, const uint16_t* __restrict__ BT,
               uint16_t* __restrict__ C, int N)
{
  __shared__ __align__(16) uint16_t As[4096];   // [128 rows][32 k] linear, swizzled
  __shared__ __align__(16) uint16_t Bs[4096];
  const int tid = threadIdx.x, lane = tid & 63, wave = tid >> 6;
  const int wr = wave >> 1, wc = wave & 1;
  const long m0 = (long)blockIdx.y * 128;
  const int  n0 = blockIdx.x * 128;

  // staging: wave covers rows [wave*32, wave*32+32) via 2 loads of 16 rows
  const int rl0 = wave*32 + (lane >> 2);
  const int rl1 = rl0 + 16;
  const int sg0 = (lane & 3) ^ ((rl0 >> 1) & 3);   // logical 16B-seg this lane fetches
  const int sg1 = (lane & 3) ^ ((rl1 >> 1) & 3);
  const uint16_t* ga0 = A + (m0 + rl0)*256 + sg0*8;
  const uint16_t* ga1 = A + (m0 + rl1)*256 + sg1*8;
  const uint16_t* gb0 = BT + (long)(n0 + rl0)*256 + sg0*8;
  const uint16_t* gb1 = BT + (long)(n0 + rl1)*256 + sg1*8;
  uint16_t* lA0 = As + wave*1024;          // wave-uniform LDS bases (1024B windows)
  uint16_t* lA1 = As + wave*1024 + 512;
  uint16_t* lB0 = Bs + wave*1024;
  uint16_t* lB1 = Bs + wave*1024 + 512;

  f32x4 acc[4][4];
  #pragma unroll
  for (int i=0;i<4;i++)
    #pragma unroll
    for (int j=0;j<4;j++) acc[i][j] = (f32x4){0.f,0.f,0.f,0.f};

  // fragment read offsets (u16 units), swizzle-matched
  const int l15 = lane & 15, lseg = lane >> 4;
  int aoff[4], boff[4];
  #pragma unroll
  for (int i=0;i<4;i++){ const int m = wr*64 + i*16 + l15; aoff[i] = m*32 + ((lseg ^ ((m>>1)&3))<<3); }
  #pragma unroll
  for (int j=0;j<4;j++){ const int n = wc*64 + j*16 + l15; boff[j] = n*32 + ((lseg ^ ((n>>1)&3))<<3); }

  for (int ks = 0; ks < 256; ks += 32) {
    gload16(ga0 + ks, lA0);
    gload16(ga1 + ks, lA1);
    gload16(gb0 + ks, lB0);
    gload16(gb1 + ks, lB1);
    __syncthreads();                       // compiler drains vmcnt before barrier
    bf16x8 af[4], bfv[4];
    #pragma unroll
    for (int i=0;i<4;i++) af[i]  = *reinterpret_cast<const bf16x8*>(&As[aoff[i]]);
    #pragma unroll
    for (int j=0;j<4;j++) bfv[j] = *reinterpret_cast<const bf16x8*>(&Bs[boff[j]]);
    #pragma unroll
    for (int i=0;i<4;i++)
      #pragma unroll
      for (int j=0;j<4;j++)
        acc[i][j] = __builtin_amdgcn_mfma_f32_16x16x32_bf16(af[i], bfv[j], acc[i][j], 0, 0, 0);
    __syncthreads();
  }

  const int rquad = lane >> 4;
  #pragma unroll
  for (int j=0;j<4;j++){
    const int col = n0 + wc*64 + j*16 + l15;
    #pragma unroll
    for (int i=0;i<4;i++){
      const long rbase = m0 + wr*64 + i*16 + rquad*4;
      #pragma unroll
      for (int r=0;r<4;r++)
        C[(rbase + r)*N + col] = f2bf(acc[i][j][r]);
    }
  }
}

// ---------------------------------------------------------------------------
// Deterministic CSR inversion, fully parallel (rank-based stable fill).
// One block per (t,b), 512 threads.
__global__ void build_csr(const int* __restrict__ td_g, const int* __restrict__ tr_g,
                          const int* __restrict__ tl_g,
                          int* __restrict__ csr_off, int* __restrict__ csr_val){
  const int t = blockIdx.x >> 6;
  const int b = blockIdx.x & 63;
  __shared__ int ids[S_];
  __shared__ int cnt[S_];
  __shared__ int off[S_];
  const int s = threadIdx.x;                      // 512 threads
  const int* srcs[3] = {td_g, tr_g, tl_g};
  for (int arr = 0; arr < 3; ++arr) {
    const int myid = srcs[arr][((long)b*T_ + t)*S_ + s];   // layout [B][T][S]
    ids[s] = myid;
    cnt[s] = 0;
    __syncthreads();
    atomicAdd(&cnt[myid], 1);
    __syncthreads();
    // rank = #{s' < s : ids[s'] == myid}; uniform ids[i] read = LDS broadcast
    int rank = 0;
    #pragma unroll 8
    for (int i = 0; i < S_; ++i) rank += (i < s && ids[i] == myid) ? 1 : 0;
    // inclusive scan of cnt -> off
    off[s] = cnt[s];
    __syncthreads();
    for (int w = 1; w < S_; w <<= 1){
      const int v = (s >= w) ? off[s-w] : 0;
      __syncthreads();
      off[s] += v;
      __syncthreads();
    }
    const long base = (((long)arr*T_ + t)*B_ + b);
    int* offs = csr_off + base*(S_+1);
    int* vals = csr_val + base*S_;
    offs[s] = off[s] - cnt[s];                    // exclusive
    if (s == S_-1) offs[S_] = off[s];
    vals[(off[myid] - cnt[myid]) + rank] = s;     // stable: ascending source order
    __syncthreads();
  }
}

// ---------------------------------------------------------------------------
// Per-step destination-side update for rows [row0, row0+grid). Thread j = channel.
__global__ __launch_bounds__(256)
void step_update(const uint16_t* __restrict__ h_in, const float* __restrict__ c_in,
                 uint16_t* __restrict__ h_out, float* __restrict__ c_out,
                 const uint16_t* __restrict__ P,      // [Mc][2048] bf16, chunk-local rows
                 const uint16_t* __restrict__ ioux,   // [M][768]  bf16
                 const uint16_t* __restrict__ fx,     // [M][256]  bf16
                 const int* __restrict__ csr_off, const int* __restrict__ csr_val,
                 const int* __restrict__ tr_g, const int* __restrict__ tl_g,
                 int t, int row0)
{
  const long bs = (long)row0 + blockIdx.x;
  const int b = (int)(bs >> 9), s = (int)(bs & 511);
  const int j = threadIdx.x;          // 0..255

  const int* off_td = csr_off + (((long)0*T_ + t)*B_ + b)*(S_+1);
  const int td0 = off_td[s], td1 = off_td[s+1];
  const bool masked = (s != 0) && (td1 > td0);
  if (!masked) {
    h_out[bs*256 + j] = h_in[bs*256 + j];
    c_out[bs*256 + j] = c_in[bs*256 + j];
    return;
  }
  const int* off_tr = csr_off + (((long)1*T_ + t)*B_ + b)*(S_+1);
  const int* off_tl = csr_off + (((long)2*T_ + t)*B_ + b)*(S_+1);
  const int* val_td = csr_val + (((long)0*T_ + t)*B_ + b)*S_;
  const int* val_tr = csr_val + (((long)1*T_ + t)*B_ + b)*S_;
  const int* val_tl = csr_val + (((long)2*T_ + t)*B_ + b)*S_;

  const long lbase = (long)(b<<9) - row0;             // chunk-local row base for P

  const long ib = bs*768;
  float ai = bf2f(ioux[ib + j]);
  float ao = bf2f(ioux[ib + 256 + j]);
  float au = bf2f(ioux[ib + 512 + j]);
  for (int p = off_tr[s]; p < off_tr[s+1]; ++p) {     // sources s' with tr[s']==s
    const long pr = (lbase + val_tr[p]) * NP_;
    ai += bf2f(P[pr + j]); ao += bf2f(P[pr + 256 + j]); au += bf2f(P[pr + 512 + j]);
  }
  for (int p = off_tl[s]; p < off_tl[s+1]; ++p) {     // sources s' with tl[s']==s
    const long pr = (lbase + val_tl[p]) * NP_;
    ai += bf2f(P[pr + 768 + j]); ao += bf2f(P[pr + 1024 + j]); au += bf2f(P[pr + 1280 + j]);
  }
  const float gi = sigm(ai);
  const float go = sigm(ao);
  const float gu = tanhf(au);
  const float fxv = bf2f(fx[bs*256 + j]);             // f_x at the DESTINATION row
  float cacc = gi * gu;
  const int* trrow = tr_g + ((long)b*T_ + t)*S_;
  const int* tlrow = tl_g + ((long)b*T_ + t)*S_;
  for (int p = td0; p < td1; ++p) {                   // children s' with td[s']==s
    const int sp = val_td[p];
    const long prr = (lbase + trrow[sp]) * NP_;       // gather P_f01 at tr[s']
    const long prl = (lbase + tlrow[sp]) * NP_;       // gather P_f23 at tl[s']
    const float f = sigm(fxv + bf2f(P[prr + 1536 + j]) + bf2f(P[prl + 1792 + j]));
    cacc += f * c_in[((long)(b<<9) + sp)*256 + j];
  }
  h_out[bs*256 + j] = f2bf(go * tanhf(cacc));
  c_out[bs*256 + j] = cacc;
}

// ---------------------------------------------------------------------------
__global__ void root_kernel(const uint16_t* __restrict__ h, const int* __restrict__ td_g,
                            float* __restrict__ out_root){
  const int b = blockIdx.x;
  __shared__ int red[256];
  const int* td = td_g + ((long)b*T_ + (T_-1))*S_;
  int m = 0;
  for (int s = threadIdx.x; s < S_; s += 256) m = max(m, td[s]);
  red[threadIdx.x] = m; __syncthreads();
  for (int w = 128; w > 0; w >>= 1){
    if (threadIdx.x < w) red[threadIdx.x] = max(red[threadIdx.x], red[threadIdx.x+w]);
    __syncthreads();
  }
  const int root = red[0];
  out_root[b*256 + threadIdx.x] = bf2f(h[((long)b*512 + root)*256 + threadIdx.x]);
}

// ---------------------------------------------------------------------------
extern "C" void kernel_launch(void* const* d_in, const int* in_sizes, int n_in,
                              void* d_out, int out_size, void* d_ws, size_t ws_size,
                              hipStream_t stream) {
  const int*   input_ids  = (const int*)  d_in[0];
  const int*   tree_ids   = (const int*)  d_in[1];
  const int*   tree_ids_r = (const int*)  d_in[2];
  const int*   tree_ids_l = (const int*)  d_in[3];
  const float* emb        = (const float*)d_in[4];
  const float* W_ioux     = (const float*)d_in[5];
  const float* b_ioux     = (const float*)d_in[6];
  const float* U_iou_r    = (const float*)d_in[7];
  const float* U_iou_l    = (const float*)d_in[8];
  const float* W_f        = (const float*)d_in[9];
  const float* b_f        = (const float*)d_in[10];
  const float* U_f0       = (const float*)d_in[11];
  const float* U_f1       = (const float*)d_in[12];
  const float* U_f2       = (const float*)d_in[13];
  const float* U_f3       = (const float*)d_in[14];
  float* out = (float*)d_out;                  // FP32 outputs: h | c | h_root

  // --- workspace layout: fixed ~179 MB + adaptive P chunk ---
  size_t woff = 0;
  auto alloc = [&](size_t bytes)->char*{
    char* p = (char*)d_ws + woff; woff += (bytes + 255) & ~(size_t)255; return p;
  };
  uint16_t* ioux   = (uint16_t*)alloc((size_t)M_*768*2);      // 50.3 MB
  uint16_t* fx     = (uint16_t*)alloc((size_t)M_*256*2);      // 16.8 MB
  uint16_t* hA     = (uint16_t*)alloc((size_t)M_*256*2);      // 16.8 MB (hA,cA contiguous)
  float*    cA     = (float*)   alloc((size_t)M_*256*4);      // 33.6 MB
  uint16_t* hB     = (uint16_t*)alloc((size_t)M_*256*2);
  float*    cB     = (float*)   alloc((size_t)M_*256*4);
  int* csr_off     = (int*)     alloc((size_t)3*T_*B_*(S_+1)*4);
  int* csr_val     = (int*)     alloc((size_t)3*T_*B_*S_*4);
  uint16_t* UcatT  = (uint16_t*)alloc((size_t)NP_*256*2);     //  1.05 MB
  uint16_t* WiouxT = (uint16_t*)alloc((size_t)768*256*2);     //  0.39 MB
  uint16_t* WfT    = (uint16_t*)alloc((size_t)256*256*2);     //  0.13 MB
  int CB = 64;                                                // batches per P chunk
  while (CB > 1 && woff + (size_t)CB*S_*NP_*2 > ws_size) CB >>= 1;
  uint16_t* P      = (uint16_t*)alloc((size_t)CB*S_*NP_*2);   // ≤134 MB (bf16)

  // --- setup: transposed bf16 weights, then MFMA setup GEMMs ---
  build_ucatT<<<2048, 256, 0, stream>>>(U_iou_r, U_iou_l, U_f0, U_f1, U_f2, U_f3, UcatT);
  transpose_bf16<<<768, 256, 0, stream>>>(W_ioux, WiouxT, 768);
  transpose_bf16<<<256, 256, 0, stream>>>(W_f, WfT, 256);
  mfma_gemm<0><<<dim3(768/128, M_/128), 256, 0, stream>>>((const char*)emb, input_ids, WiouxT, b_ioux, ioux, 768);
  mfma_gemm<0><<<dim3(256/128, M_/128), 256, 0, stream>>>((const char*)emb, input_ids, WfT, b_f, fx, 256);
  build_csr<<<T_*B_, S_, 0, stream>>>(tree_ids, tree_ids_r, tree_ids_l, csr_off, csr_val);
  zero16<<<12288, 256, 0, stream>>>((uint4*)hA, 3145728L);   // zero hA+cA (contiguous 50.3MB)

  // --- T sequential steps, ping-pong state, batch-chunked projection ---
  uint16_t *hc = hA, *hn = hB; float *cc = cA, *cn = cB;
  for (int t = 0; t < T_; ++t) {
    for (int b0 = 0; b0 < B_; b0 += CB) {
      const int row0 = b0 * S_;
      const int Mc   = CB * S_;
      gemm_step<<<dim3(NP_/128, Mc/128), 256, 0, stream>>>(
          hc + (long)row0*256, UcatT, P, NP_);
      step_update<<<Mc, 256, 0, stream>>>(hc, cc, hn, cn, P, ioux, fx,
                                          csr_off, csr_val, tree_ids_r, tree_ids_l,
                                          t, row0);
    }
    uint16_t* th = hc; hc = hn; hn = th;
    float*    tc = cc; cc = cn; cn = tc;
  }

  // --- outputs (fp32): h | c | h_root ---
  bf16_to_f32<<<8192, 256, 0, stream>>>(hc, out, (long)M_*256);                        // h
  copy16<<<8192, 256, 0, stream>>>((const uint4*)cc, (uint4*)(out + (long)M_*256), 2097152L); // c
  root_kernel<<<B_, 256, 0, stream>>>(hc, tree_ids, out + 2L*M_*256);                  // h_root
}

// Round 7
// 1416.379 us; speedup vs baseline: 3.7481x; 1.1673x over previous
//
#include <hip/hip_runtime.h>
#include <stdint.h>

#define B_ 64
#define S_ 512
#define T_ 12
#define M_ (B_*S_)      // 32768 rows
#define NP_ 2048        // width of per-step projection P

typedef __attribute__((ext_vector_type(8))) short bf16x8;   // 8 bf16 = 4 VGPR
typedef __attribute__((ext_vector_type(4))) float f32x4;    // MFMA accumulator

__device__ __forceinline__ uint16_t f2bf(float f){
  union { float f; uint32_t u; } x; x.f = f;
  uint32_t r = x.u + 0x7FFFu + ((x.u >> 16) & 1u);   // RTNE
  return (uint16_t)(r >> 16);
}
__device__ __forceinline__ float bf2f(uint16_t u){
  union { float f; uint32_t u; } x; x.u = ((uint32_t)u) << 16; return x.f;
}
__device__ __forceinline__ float sigm(float x){ return 1.0f/(1.0f + expf(-x)); }
__device__ __forceinline__ float4 bf4(const uint16_t* p){
  const ushort4 v = *reinterpret_cast<const ushort4*>(p);
  return make_float4(bf2f(v.x), bf2f(v.y), bf2f(v.z), bf2f(v.w));
}

// async global->LDS, 16B per lane; LDS dest = wave-uniform base + lane*16
__device__ __forceinline__ void gload16(const uint16_t* g, uint16_t* l){
  __builtin_amdgcn_global_load_lds(
      (const __attribute__((address_space(1))) uint32_t*)g,
      (__attribute__((address_space(3))) uint32_t*)l, 16, 0, 0);
}

// ---------------------------------------------------------------------------
__global__ void zero16(uint4* __restrict__ p, long n16){
  const long i = (long)blockIdx.x * 256 + threadIdx.x;
  if (i < n16) p[i] = make_uint4(0,0,0,0);
}
__global__ void copy16(const uint4* __restrict__ s, uint4* __restrict__ d, long n16){
  const long i = (long)blockIdx.x * 256 + threadIdx.x;
  if (i < n16) d[i] = s[i];
}
__global__ void bf16_to_f32(const uint16_t* __restrict__ src, float* __restrict__ dst, long n){
  const long i = ((long)blockIdx.x * 256 + threadIdx.x) * 4;
  if (i + 3 < n) {
    const float4 o = bf4(src + i);
    *reinterpret_cast<float4*>(dst + i) = o;
  }
}

// ---------------------------------------------------------------------------
// UcatT[2048][256] bf16, UcatT[n][k] = [U_iou_r | U_iou_l | U_f0+U_f1 | U_f2+U_f3][k][n]
__global__ void build_ucatT(const float* __restrict__ Ur, const float* __restrict__ Ul,
                            const float* __restrict__ f0, const float* __restrict__ f1,
                            const float* __restrict__ f2, const float* __restrict__ f3,
                            uint16_t* __restrict__ UcatT){
  const int idx = blockIdx.x * 256 + threadIdx.x;   // 2048*256 total
  const int n = idx >> 8, k = idx & 255;
  float v;
  if (n < 768)        v = Ur[k*768 + n];
  else if (n < 1536)  v = Ul[k*768 + (n-768)];
  else if (n < 1792) { int j = n-1536; v = f0[k*256+j] + f1[k*256+j]; }
  else               { int j = n-1792; v = f2[k*256+j] + f3[k*256+j]; }
  UcatT[(long)n*256 + k] = f2bf(v);
}

// WallT[1024][256] bf16 = [W_ioux | W_f]^T   (grid = 1024, 256 threads)
__global__ void build_wallT(const float* __restrict__ Wioux, const float* __restrict__ Wf,
                            uint16_t* __restrict__ WT){
  const int idx = blockIdx.x * 256 + threadIdx.x;   // 1024*256 total
  const int n = idx >> 8, k = idx & 255;
  const float v = (n < 768) ? Wioux[(long)k*768 + n] : Wf[(long)k*256 + (n-768)];
  WT[(long)n*256 + k] = f2bf(v);
}

// ---------------------------------------------------------------------------
// Setup-path MFMA GEMM (fp32 A with row gather): padded-LDS manual staging.
// bias: col<split -> bias[col], else bias2[col-split].
__global__ __launch_bounds__(256)
void mfma_gemm(const float* __restrict__ Af, const int* __restrict__ row_ids,
               const uint16_t* __restrict__ BT,
               const float* __restrict__ bias, const float* __restrict__ bias2, int split,
               uint16_t* __restrict__ C, int N)
{
  __shared__ uint16_t As[128][40];   // [m][k], +8 pad -> 80B rows
  __shared__ uint16_t Bs[128][40];   // [n][k]
  const int tid  = threadIdx.x;
  const int lane = tid & 63;
  const int wave = tid >> 6;
  const int wr = wave >> 1, wc = wave & 1;
  const long m0 = (long)blockIdx.y * 128;
  const int  n0 = blockIdx.x * 128;

  const int srow = tid >> 1;
  const int sseg = (tid & 1) * 16;
  const long arid = (long)row_ids[m0 + srow];

  f32x4 acc[4][4];
  #pragma unroll
  for (int i=0;i<4;i++)
    #pragma unroll
    for (int j=0;j<4;j++) acc[i][j] = (f32x4){0.f,0.f,0.f,0.f};

  for (int ks = 0; ks < 256; ks += 32) {
    {
      const float* sf = Af + arid*256 + ks + sseg;
      uint16_t tmp[16];
      #pragma unroll
      for (int e=0;e<16;e++) tmp[e] = f2bf(sf[e]);
      *reinterpret_cast<uint4*>(&As[srow][sseg])     = *reinterpret_cast<const uint4*>(&tmp[0]);
      *reinterpret_cast<uint4*>(&As[srow][sseg + 8]) = *reinterpret_cast<const uint4*>(&tmp[8]);
    }
    {
      const uint16_t* src = BT + (long)(n0 + srow)*256 + ks + sseg;
      *reinterpret_cast<uint4*>(&Bs[srow][sseg])     = *reinterpret_cast<const uint4*>(src);
      *reinterpret_cast<uint4*>(&Bs[srow][sseg + 8]) = *reinterpret_cast<const uint4*>(src + 8);
    }
    __syncthreads();

    bf16x8 af[4], bfv[4];
    #pragma unroll
    for (int i=0;i<4;i++)
      af[i] = *reinterpret_cast<const bf16x8*>(&As[wr*64 + i*16 + (lane & 15)][(lane >> 4)*8]);
    #pragma unroll
    for (int j=0;j<4;j++)
      bfv[j] = *reinterpret_cast<const bf16x8*>(&Bs[wc*64 + j*16 + (lane & 15)][(lane >> 4)*8]);
    #pragma unroll
    for (int i=0;i<4;i++)
      #pragma unroll
      for (int j=0;j<4;j++)
        acc[i][j] = __builtin_amdgcn_mfma_f32_16x16x32_bf16(af[i], bfv[j], acc[i][j], 0, 0, 0);
    __syncthreads();
  }

  const int col16 = lane & 15, rquad = lane >> 4;
  #pragma unroll
  for (int j=0;j<4;j++){
    const int col = n0 + wc*64 + j*16 + col16;
    const float bv = (col < split) ? bias[col] : bias2[col - split];
    #pragma unroll
    for (int i=0;i<4;i++){
      const long rbase = m0 + wr*64 + i*16 + rquad*4;
      #pragma unroll
      for (int r=0;r<4;r++)
        C[(rbase + r)*N + col] = f2bf(acc[i][j][r] + bv);
    }
  }
}

// ---------------------------------------------------------------------------
// Step-path MFMA GEMM (bf16 A, no gather): global_load_lds staging, linear LDS,
// XOR seg-swizzle (seg' = seg ^ ((row>>1)&3)) applied to global source AND ds_read.
__global__ __launch_bounds__(256)
void gemm_step(const uint16_t* __restrict__ A, const uint16_t* __restrict__ BT,
               uint16_t* __restrict__ C, int N)
{
  __shared__ __align__(16) uint16_t As[4096];   // [128 rows][32 k] linear, swizzled
  __shared__ __align__(16) uint16_t Bs[4096];
  const int tid = threadIdx.x, lane = tid & 63, wave = tid >> 6;
  const int wr = wave >> 1, wc = wave & 1;
  const long m0 = (long)blockIdx.y * 128;
  const int  n0 = blockIdx.x * 128;

  // staging: wave covers rows [wave*32, wave*32+32) via 2 loads of 16 rows
  const int rl0 = wave*32 + (lane >> 2);
  const int rl1 = rl0 + 16;
  const int sg0 = (lane & 3) ^ ((rl0 >> 1) & 3);   // logical 16B-seg this lane fetches
  const int sg1 = (lane & 3) ^ ((rl1 >> 1) & 3);
  const uint16_t* ga0 = A + (m0 + rl0)*256 + sg0*8;
  const uint16_t* ga1 = A + (m0 + rl1)*256 + sg1*8;
  const uint16_t* gb0 = BT + (long)(n0 + rl0)*256 + sg0*8;
  const uint16_t* gb1 = BT + (long)(n0 + rl1)*256 + sg1*8;
  uint16_t* lA0 = As + wave*1024;          // wave-uniform LDS bases (1024B windows)
  uint16_t* lA1 = As + wave*1024 + 512;
  uint16_t* lB0 = Bs + wave*1024;
  uint16_t* lB1 = Bs + wave*1024 + 512;

  f32x4 acc[4][4];
  #pragma unroll
  for (int i=0;i<4;i++)
    #pragma unroll
    for (int j=0;j<4;j++) acc[i][j] = (f32x4){0.f,0.f,0.f,0.f};

  // fragment read offsets (u16 units), swizzle-matched
  const int l15 = lane & 15, lseg = lane >> 4;
  int aoff[4], boff[4];
  #pragma unroll
  for (int i=0;i<4;i++){ const int m = wr*64 + i*16 + l15; aoff[i] = m*32 + ((lseg ^ ((m>>1)&3))<<3); }
  #pragma unroll
  for (int j=0;j<4;j++){ const int n = wc*64 + j*16 + l15; boff[j] = n*32 + ((lseg ^ ((n>>1)&3))<<3); }

  for (int ks = 0; ks < 256; ks += 32) {
    gload16(ga0 + ks, lA0);
    gload16(ga1 + ks, lA1);
    gload16(gb0 + ks, lB0);
    gload16(gb1 + ks, lB1);
    __syncthreads();                       // compiler drains vmcnt before barrier
    bf16x8 af[4], bfv[4];
    #pragma unroll
    for (int i=0;i<4;i++) af[i]  = *reinterpret_cast<const bf16x8*>(&As[aoff[i]]);
    #pragma unroll
    for (int j=0;j<4;j++) bfv[j] = *reinterpret_cast<const bf16x8*>(&Bs[boff[j]]);
    #pragma unroll
    for (int i=0;i<4;i++)
      #pragma unroll
      for (int j=0;j<4;j++)
        acc[i][j] = __builtin_amdgcn_mfma_f32_16x16x32_bf16(af[i], bfv[j], acc[i][j], 0, 0, 0);
    __syncthreads();
  }

  const int rquad = lane >> 4;
  #pragma unroll
  for (int j=0;j<4;j++){
    const int col = n0 + wc*64 + j*16 + l15;
    #pragma unroll
    for (int i=0;i<4;i++){
      const long rbase = m0 + wr*64 + i*16 + rquad*4;
      #pragma unroll
      for (int r=0;r<4;r++)
        C[(rbase + r)*N + col] = f2bf(acc[i][j][r]);
    }
  }
}

// ---------------------------------------------------------------------------
// Deterministic CSR inversion, chunked-histogram rank (no serial section).
// One block per (t,b), 512 threads; chunk q = wave = s>>6.
__global__ void build_csr(const int* __restrict__ td_g, const int* __restrict__ tr_g,
                          const int* __restrict__ tl_g,
                          int* __restrict__ csr_off, int* __restrict__ csr_val){
  const int t = blockIdx.x >> 6;
  const int b = blockIdx.x & 63;
  __shared__ int ids[S_];
  __shared__ int cnt[S_];
  __shared__ int off[S_];
  __shared__ int chc[8][S_];                      // per-chunk histogram
  const int s = threadIdx.x;                      // 512 threads
  const int q = s >> 6;                           // chunk = wave index
  const int* srcs[3] = {td_g, tr_g, tl_g};
  for (int arr = 0; arr < 3; ++arr) {
    const int myid = srcs[arr][((long)b*T_ + t)*S_ + s];   // layout [B][T][S]
    ids[s] = myid;
    cnt[s] = 0;
    #pragma unroll
    for (int qq=0; qq<8; qq++) chc[qq][s] = 0;
    __syncthreads();
    atomicAdd(&cnt[myid], 1);
    atomicAdd(&chc[q][myid], 1);
    __syncthreads();
    // stable rank: earlier chunks' counts + in-chunk scan (<=63 iters)
    int rank = 0;
    for (int qq = 0; qq < q; ++qq) rank += chc[qq][myid];
    for (int i = q*64; i < s; ++i) rank += (ids[i] == myid) ? 1 : 0;
    // inclusive scan of cnt -> off
    off[s] = cnt[s];
    __syncthreads();
    for (int w = 1; w < S_; w <<= 1){
      const int v = (s >= w) ? off[s-w] : 0;
      __syncthreads();
      off[s] += v;
      __syncthreads();
    }
    const long base = (((long)arr*T_ + t)*B_ + b);
    int* offs = csr_off + base*(S_+1);
    int* vals = csr_val + base*S_;
    offs[s] = off[s] - cnt[s];                    // exclusive
    if (s == S_-1) offs[S_] = off[s];
    vals[(off[myid] - cnt[myid]) + rank] = s;     // stable: ascending source order
    __syncthreads();
  }
}

// ---------------------------------------------------------------------------
// Per-step destination-side update. 1 wave per row (4 rows/block), lane owns 4 channels.
__global__ __launch_bounds__(256)
void step_update(const uint16_t* __restrict__ h_in, const float* __restrict__ c_in,
                 uint16_t* __restrict__ h_out, float* __restrict__ c_out,
                 const uint16_t* __restrict__ P,      // [Mc][2048] bf16, chunk-local rows
                 const uint16_t* __restrict__ ioufx,  // [M][1024] bf16: i|o|u|fx
                 const int* __restrict__ csr_off, const int* __restrict__ csr_val,
                 const int* __restrict__ tr_g, const int* __restrict__ tl_g,
                 int t, int row0)
{
  const int wave = threadIdx.x >> 6, lane = threadIdx.x & 63;
  const long bs = (long)row0 + (long)blockIdx.x*4 + wave;
  const int b = (int)(bs >> 9), s = (int)(bs & 511);
  const int j = lane * 4;             // channel group

  const int* off_td = csr_off + (((long)0*T_ + t)*B_ + b)*(S_+1);
  const int td0 = off_td[s], td1 = off_td[s+1];
  const bool masked = (s != 0) && (td1 > td0);
  if (!masked) {
    *reinterpret_cast<ushort4*>(h_out + bs*256 + j) =
        *reinterpret_cast<const ushort4*>(h_in + bs*256 + j);
    *reinterpret_cast<float4*>(c_out + bs*256 + j) =
        *reinterpret_cast<const float4*>(c_in + bs*256 + j);
    return;
  }
  const int* off_tr = csr_off + (((long)1*T_ + t)*B_ + b)*(S_+1);
  const int* off_tl = csr_off + (((long)2*T_ + t)*B_ + b)*(S_+1);
  const int* val_td = csr_val + (((long)0*T_ + t)*B_ + b)*S_;
  const int* val_tr = csr_val + (((long)1*T_ + t)*B_ + b)*S_;
  const int* val_tl = csr_val + (((long)2*T_ + t)*B_ + b)*S_;

  const long lbase = (long)(b<<9) - row0;             // chunk-local row base for P

  const long ib = bs*1024;
  float4 ai = bf4(ioufx + ib + j);
  float4 ao = bf4(ioufx + ib + 256 + j);
  float4 au = bf4(ioufx + ib + 512 + j);
  for (int p = off_tr[s]; p < off_tr[s+1]; ++p) {     // sources s' with tr[s']==s
    const long pr = (lbase + val_tr[p]) * NP_;
    const float4 x = bf4(P + pr + j), y = bf4(P + pr + 256 + j), z = bf4(P + pr + 512 + j);
    ai.x+=x.x; ai.y+=x.y; ai.z+=x.z; ai.w+=x.w;
    ao.x+=y.x; ao.y+=y.y; ao.z+=y.z; ao.w+=y.w;
    au.x+=z.x; au.y+=z.y; au.z+=z.z; au.w+=z.w;
  }
  for (int p = off_tl[s]; p < off_tl[s+1]; ++p) {     // sources s' with tl[s']==s
    const long pr = (lbase + val_tl[p]) * NP_;
    const float4 x = bf4(P + pr + 768 + j), y = bf4(P + pr + 1024 + j), z = bf4(P + pr + 1280 + j);
    ai.x+=x.x; ai.y+=x.y; ai.z+=x.z; ai.w+=x.w;
    ao.x+=y.x; ao.y+=y.y; ao.z+=y.z; ao.w+=y.w;
    au.x+=z.x; au.y+=z.y; au.z+=z.z; au.w+=z.w;
  }
  float4 cacc;
  cacc.x = sigm(ai.x)*tanhf(au.x); cacc.y = sigm(ai.y)*tanhf(au.y);
  cacc.z = sigm(ai.z)*tanhf(au.z); cacc.w = sigm(ai.w)*tanhf(au.w);
  const float4 fxv = bf4(ioufx + ib + 768 + j);       // f_x at the DESTINATION row
  const int* trrow = tr_g + ((long)b*T_ + t)*S_;
  const int* tlrow = tl_g + ((long)b*T_ + t)*S_;
  for (int p = td0; p < td1; ++p) {                   // children s' with td[s']==s
    const int sp = val_td[p];
    const long prr = (lbase + trrow[sp]) * NP_ + 1536;  // gather P_f01 at tr[s']
    const long prl = (lbase + tlrow[sp]) * NP_ + 1792;  // gather P_f23 at tl[s']
    const float4 pa = bf4(P + prr + j), pb = bf4(P + prl + j);
    const float4 cv = *reinterpret_cast<const float4*>(c_in + ((long)(b<<9) + sp)*256 + j);
    cacc.x += sigm(fxv.x + pa.x + pb.x) * cv.x;
    cacc.y += sigm(fxv.y + pa.y + pb.y) * cv.y;
    cacc.z += sigm(fxv.z + pa.z + pb.z) * cv.z;
    cacc.w += sigm(fxv.w + pa.w + pb.w) * cv.w;
  }
  ushort4 ho;
  ho.x = f2bf(sigm(ao.x) * tanhf(cacc.x));
  ho.y = f2bf(sigm(ao.y) * tanhf(cacc.y));
  ho.z = f2bf(sigm(ao.z) * tanhf(cacc.z));
  ho.w = f2bf(sigm(ao.w) * tanhf(cacc.w));
  *reinterpret_cast<ushort4*>(h_out + bs*256 + j) = ho;
  *reinterpret_cast<float4*>(c_out + bs*256 + j) = cacc;
}

// ---------------------------------------------------------------------------
__global__ void root_kernel(const uint16_t* __restrict__ h, const int* __restrict__ td_g,
                            float* __restrict__ out_root){
  const int b = blockIdx.x;
  __shared__ int red[256];
  const int* td = td_g + ((long)b*T_ + (T_-1))*S_;
  int m = 0;
  for (int s = threadIdx.x; s < S_; s += 256) m = max(m, td[s]);
  red[threadIdx.x] = m; __syncthreads();
  for (int w = 128; w > 0; w >>= 1){
    if (threadIdx.x < w) red[threadIdx.x] = max(red[threadIdx.x], red[threadIdx.x+w]);
    __syncthreads();
  }
  const int root = red[0];
  out_root[b*256 + threadIdx.x] = bf2f(h[((long)b*512 + root)*256 + threadIdx.x]);
}

// ---------------------------------------------------------------------------
extern "C" void kernel_launch(void* const* d_in, const int* in_sizes, int n_in,
                              void* d_out, int out_size, void* d_ws, size_t ws_size,
                              hipStream_t stream) {
  const int*   input_ids  = (const int*)  d_in[0];
  const int*   tree_ids   = (const int*)  d_in[1];
  const int*   tree_ids_r = (const int*)  d_in[2];
  const int*   tree_ids_l = (const int*)  d_in[3];
  const float* emb        = (const float*)d_in[4];
  const float* W_ioux     = (const float*)d_in[5];
  const float* b_ioux     = (const float*)d_in[6];
  const float* U_iou_r    = (const float*)d_in[7];
  const float* U_iou_l    = (const float*)d_in[8];
  const float* W_f        = (const float*)d_in[9];
  const float* b_f        = (const float*)d_in[10];
  float* out = (float*)d_out;                  // FP32 outputs: h | c | h_root

  // --- workspace layout: fixed ~179 MB + adaptive P chunk ---
  size_t woff = 0;
  auto alloc = [&](size_t bytes)->char*{
    char* p = (char*)d_ws + woff; woff += (bytes + 255) & ~(size_t)255; return p;
  };
  uint16_t* ioufx  = (uint16_t*)alloc((size_t)M_*1024*2);     // 67.1 MB: i|o|u|fx
  uint16_t* hA     = (uint16_t*)alloc((size_t)M_*256*2);      // 16.8 MB (hA,cA contiguous)
  float*    cA     = (float*)   alloc((size_t)M_*256*4);      // 33.6 MB
  uint16_t* hB     = (uint16_t*)alloc((size_t)M_*256*2);
  float*    cB     = (float*)   alloc((size_t)M_*256*4);
  int* csr_off     = (int*)     alloc((size_t)3*T_*B_*(S_+1)*4);
  int* csr_val     = (int*)     alloc((size_t)3*T_*B_*S_*4);
  uint16_t* UcatT  = (uint16_t*)alloc((size_t)NP_*256*2);     //  1.05 MB
  uint16_t* WallT  = (uint16_t*)alloc((size_t)1024*256*2);    //  0.52 MB
  int CB = 64;                                                // batches per P chunk
  while (CB > 1 && woff + (size_t)CB*S_*NP_*2 > ws_size) CB >>= 1;
  uint16_t* P      = (uint16_t*)alloc((size_t)CB*S_*NP_*2);   // ≤134 MB (bf16)

  // --- setup: transposed bf16 weights, merged setup GEMM ---
  build_ucatT<<<2048, 256, 0, stream>>>(U_iou_r, U_iou_l,
      (const float*)d_in[11], (const float*)d_in[12], (const float*)d_in[13], (const float*)d_in[14],
      UcatT);
  build_wallT<<<1024, 256, 0, stream>>>(W_ioux, W_f, WallT);
  mfma_gemm<<<dim3(1024/128, M_/128), 256, 0, stream>>>(emb, input_ids, WallT,
                                                        b_ioux, b_f, 768, ioufx, 1024);
  build_csr<<<T_*B_, S_, 0, stream>>>(tree_ids, tree_ids_r, tree_ids_l, csr_off, csr_val);
  zero16<<<12288, 256, 0, stream>>>((uint4*)hA, 3145728L);   // zero hA+cA (contiguous 50.3MB)

  // --- T sequential steps, ping-pong state, batch-chunked projection ---
  uint16_t *hc = hA, *hn = hB; float *cc = cA, *cn = cB;
  for (int t = 0; t < T_; ++t) {
    for (int b0 = 0; b0 < B_; b0 += CB) {
      const int row0 = b0 * S_;
      const int Mc   = CB * S_;
      gemm_step<<<dim3(NP_/128, Mc/128), 256, 0, stream>>>(
          hc + (long)row0*256, UcatT, P, NP_);
      step_update<<<Mc/4, 256, 0, stream>>>(hc, cc, hn, cn, P, ioufx,
                                            csr_off, csr_val, tree_ids_r, tree_ids_l,
                                            t, row0);
    }
    uint16_t* th = hc; hc = hn; hn = th;
    float*    tc = cc; cc = cn; cn = tc;
  }

  // --- outputs (fp32): h | c | h_root ---
  bf16_to_f32<<<8192, 256, 0, stream>>>(hc, out, (long)M_*256);                        // h
  copy16<<<8192, 256, 0, stream>>>((const uint4*)cc, (uint4*)(out + (long)M_*256), 2097152L); // c
  root_kernel<<<B_, 256, 0, stream>>>(hc, tree_ids, out + 2L*M_*256);                  // h_root
}